// Round 2
// baseline (211.479 us; speedup 1.0000x reference)
//
#include <hip/hip_runtime.h>
#include <math.h>

#define CAPV 0.99f

// ---------------------------------------------------------------------------
// Kernel 1: per-batch angle/diag precompute (unchanged, cost ~ few us).
//   cs[b*1024 + p]  = {cos(angles[p] + tanh(mod[b]·w_angle[p])), sin(...)}
//   diag[b*256 + c] = clip(clip(tanh(diagonal[c])) + tanh(mod[b]·w_diag[c]))
// ---------------------------------------------------------------------------
__global__ void pr_precompute(const float* __restrict__ mod,
                              const float* __restrict__ angles,
                              const float* __restrict__ diagonal,
                              const float* __restrict__ w_angle,
                              const float* __restrict__ w_diag,
                              float2* __restrict__ cs,
                              float* __restrict__ diag_out) {
    const int gid = blockIdx.x * blockDim.x + threadIdx.x;   // 0..32767
    const int b = gid >> 10;
    const int p = gid & 1023;

    const float4* m  = (const float4*)(mod + (size_t)b * 256);
    const float4* wr = (const float4*)(w_angle + (size_t)p * 256);
    float acc = 0.f;
#pragma unroll
    for (int k = 0; k < 64; ++k) {
        float4 a = m[k], c = wr[k];
        acc += a.x * c.x + a.y * c.y + a.z * c.z + a.w * c.w;
    }
    const float ang = angles[p] + tanhf(acc);
    float sv, cv;
    sincosf(ang, &sv, &cv);
    cs[gid] = make_float2(cv, sv);

    if (gid < 32 * 256) {
        const int b2 = gid >> 8;
        const int cd = gid & 255;
        const float4* m2 = (const float4*)(mod + (size_t)b2 * 256);
        const float4* w2 = (const float4*)(w_diag + (size_t)cd * 256);
        float a2 = 0.f;
#pragma unroll
        for (int k = 0; k < 64; ++k) {
            float4 u = m2[k], v = w2[k];
            a2 += u.x * v.x + u.y * v.y + u.z * v.z + u.w * v.w;
        }
        float bd = tanhf(diagonal[cd]);
        bd = fminf(fmaxf(bd, -CAPV), CAPV);
        float d = bd + tanhf(a2);
        d = fminf(fmaxf(d, -CAPV), CAPV);
        diag_out[gid] = d;
    }
}

// ---------------------------------------------------------------------------
// Kernel 2: butterfly. Thread = 32 channels x 2 points (float2 y[32]).
// Wave layout: chunk = lane>>3 (channels [chunk*32, chunk*32+32)),
//              point-pair = lane&7  -> 16 points per wave, 64 per block.
// Stages 1..5 (half<=16): register-local, compile-time indices.
// Stages 6,7,8 (half=32,64,128): partner chunk = chunk^1/^2/^4
//                                -> __shfl_xor lane masks 8/16/32.
// cs/diag LDS tables padded +1 per 16 entries: the 8 chunk-strided broadcast
// addresses (stride 128B) would otherwise all hit bank 0 (8-way conflict).
// Pair-index formulas (p = stage-global pair index, lc = local channel):
//   st 1..5: p = (st-1)*128 + chunk*16 + jj
//   st 6:    p = 640 + (chunk>>1)*32 + lc
//   st 7:    p = 768 + (chunk>>2)*64 + (chunk&1)*32 + lc
//   st 8:    p = 896 + (chunk&3)*32 + lc
// padded index p' = p + (p>>4).
// ---------------------------------------------------------------------------
__global__ __launch_bounds__(256, 4)
void pr_butterfly(const float* __restrict__ x,
                  const float2* __restrict__ cs,
                  const float* __restrict__ diag,
                  float* __restrict__ out) {
    __shared__ __align__(16) float2 cs_pad[1088];   // 1024 + 64 pad
    __shared__ __align__(16) float  diag_pad[272];  // 256 + 16 pad

    const int tid = threadIdx.x;
    const int blk = blockIdx.x;          // 2048 blocks
    const int b   = blk >> 6;            // 0..31
    const int ppB = (blk & 63) * 32;     // block's point-pair base (64 pts)

    // Stage tables into LDS with +1/16 padding.
    {
        const float2* csg = cs + (size_t)b * 1024;
#pragma unroll
        for (int i = 0; i < 4; ++i) {
            const int p = tid * 4 + i;
            cs_pad[p + (p >> 4)] = csg[p];
        }
        const int c = tid;               // 0..255
        diag_pad[c + (c >> 4)] = diag[(size_t)b * 256 + c];
    }
    __syncthreads();

    const int lane  = tid & 63;
    const int wv    = tid >> 6;
    const int chunk = lane >> 3;                  // 0..7
    const int pp    = ppB + wv * 8 + (lane & 7);  // point-pair 0..2047

    const float2* __restrict__ xb = (const float2*)x + (size_t)b * 524288;
    float2* __restrict__ ob = (float2*)out + (size_t)b * 524288;
    const unsigned coff = (unsigned)(chunk * 32) * 2048u + (unsigned)pp;

    float2 y[32];
#pragma unroll
    for (int i = 0; i < 32; ++i)
        y[i] = xb[coff + (unsigned)i * 2048u];

    // Stages 1..5 — register-local rotations (both points packed).
#pragma unroll
    for (int st = 1; st <= 5; ++st) {
        const int half  = 1 << (st - 1);
        const int pbase = (st - 1) * 136 + chunk * 17;   // padded float2 idx
#pragma unroll
        for (int jj = 0; jj < 16; ++jj) {
            const int il = ((jj >> (st - 1)) << st) | (jj & (half - 1));
            const int ir = il | half;
            const float2 a = cs_pad[pbase + jj];   // {cos, sin}
            const float2 l = y[il];
            const float2 r = y[ir];
            y[il].x = fmaf(a.x, l.x, a.y * r.x);
            y[il].y = fmaf(a.x, l.y, a.y * r.y);
            y[ir].x = fmaf(a.x, r.x, -(a.y * l.x));
            y[ir].y = fmaf(a.x, r.y, -(a.y * l.y));
        }
    }

    // Stages 6..8 — cross-lane. Own side fixed per stage: left -> +s*partner,
    // right -> -s*partner (new_right = c*r - s*l).
#pragma unroll
    for (int st = 6; st <= 8; ++st) {
        int  pbase, xmask;
        bool left;
        if (st == 6)      { pbase = 680 + (chunk >> 1) * 34;                      xmask = 8;  left = !(chunk & 1); }
        else if (st == 7) { pbase = 816 + (chunk >> 2) * 68 + (chunk & 1) * 34;   xmask = 16; left = !(chunk & 2); }
        else              { pbase = 952 + (chunk & 3) * 34;                       xmask = 32; left = !(chunk & 4); }
#pragma unroll
        for (int i = 0; i < 32; ++i) {
            const float2 a = cs_pad[pbase + i + (i >> 4)];
            const float px = __shfl_xor(y[i].x, xmask, 64);
            const float py = __shfl_xor(y[i].y, xmask, 64);
            const float se = left ? a.y : -a.y;
            y[i].x = fmaf(a.x, y[i].x, se * px);
            y[i].y = fmaf(a.x, y[i].y, se * py);
        }
    }

    // Diagonal scale + float2 store.
#pragma unroll
    for (int i = 0; i < 32; ++i) {
        const float dv = diag_pad[chunk * 34 + i + (i >> 4)];
        float2 v;
        v.x = y[i].x * dv;
        v.y = y[i].y * dv;
        ob[coff + (unsigned)i * 2048u] = v;
    }
}

// ---------------------------------------------------------------------------
extern "C" void kernel_launch(void* const* d_in, const int* in_sizes, int n_in,
                              void* d_out, int out_size, void* d_ws, size_t ws_size,
                              hipStream_t stream) {
    const float* x        = (const float*)d_in[0];  // (32,256,64,64)
    const float* mod      = (const float*)d_in[1];  // (32,256)
    const float* angles   = (const float*)d_in[2];  // (1024,)
    const float* diagonal = (const float*)d_in[3];  // (256,)
    const float* w_angle  = (const float*)d_in[4];  // (1024,256)
    const float* w_diag   = (const float*)d_in[5];  // (256,256)
    float* out = (float*)d_out;

    float2* cs   = (float2*)d_ws;                                      // 256 KB
    float*  diag = (float*)((char*)d_ws + 32 * 1024 * sizeof(float2)); // 32 KB

    pr_precompute<<<128, 256, 0, stream>>>(mod, angles, diagonal, w_angle, w_diag, cs, diag);
    pr_butterfly<<<2048, 256, 0, stream>>>(x, cs, diag, out);
}

// Round 3
// 130.779 us; speedup vs baseline: 1.6171x; 1.6171x over previous
//
#include <hip/hip_runtime.h>
#include <math.h>

#define CAPV 0.99f

// ---------------------------------------------------------------------------
// Kernel 1: per-batch angle/diag precompute (unchanged; ~few us).
//   cs[b*1024 + p]  = {cos(angles[p] + tanh(mod[b]·w_angle[p])), sin(...)}
//   diag[b*256 + c] = clip(clip(tanh(diagonal[c])) + tanh(mod[b]·w_diag[c]))
// ---------------------------------------------------------------------------
__global__ void pr_precompute(const float* __restrict__ mod,
                              const float* __restrict__ angles,
                              const float* __restrict__ diagonal,
                              const float* __restrict__ w_angle,
                              const float* __restrict__ w_diag,
                              float2* __restrict__ cs,
                              float* __restrict__ diag_out) {
    const int gid = blockIdx.x * blockDim.x + threadIdx.x;   // 0..32767
    const int b = gid >> 10;
    const int p = gid & 1023;

    const float4* m  = (const float4*)(mod + (size_t)b * 256);
    const float4* wr = (const float4*)(w_angle + (size_t)p * 256);
    float acc = 0.f;
#pragma unroll
    for (int k = 0; k < 64; ++k) {
        float4 a = m[k], c = wr[k];
        acc += a.x * c.x + a.y * c.y + a.z * c.z + a.w * c.w;
    }
    const float ang = angles[p] + tanhf(acc);
    float sv, cv;
    sincosf(ang, &sv, &cv);
    cs[gid] = make_float2(cv, sv);

    if (gid < 32 * 256) {
        const int b2 = gid >> 8;
        const int cd = gid & 255;
        const float4* m2 = (const float4*)(mod + (size_t)b2 * 256);
        const float4* w2 = (const float4*)(w_diag + (size_t)cd * 256);
        float a2 = 0.f;
#pragma unroll
        for (int k = 0; k < 64; ++k) {
            float4 u = m2[k], v = w2[k];
            a2 += u.x * v.x + u.y * v.y + u.z * v.z + u.w * v.w;
        }
        float bd = tanhf(diagonal[cd]);
        bd = fminf(fmaxf(bd, -CAPV), CAPV);
        float d = bd + tanhf(a2);
        d = fminf(fmaxf(d, -CAPV), CAPV);
        diag_out[gid] = d;
    }
}

// ---------------------------------------------------------------------------
// Kernel 2: butterfly with LDS bridge.
// Block = 256 thr, tile = 256 ch x 32 pts (32 KB LDS).
// Phase A: global->LDS via global_load_lds (128B-coalesced rows, source
//          pre-XOR-swizzled so LDS dest stays lane-linear; swz s=(row>>3)&7
//          is wave-uniform per call).
// Phase B: thread = 16 contiguous channels (A=lane>>2) x 2 pts
//          (pt = wv*8+(lane&3)*2). Stages 1-4 register-local; stages 5-8 via
//          __shfl_xor(4/8/16/32). cs/diag read from global (L1/L2-hot).
// Phase C: b64 write-back, barrier, coalesced float4 stores (inverse swizzle
//          applied to the global store address).
// Swizzle: physical float f_phys = f_log ^ (s<<2)  (bits [4:2] of pt index).
// cs pair index: p = (st-1)*128 + (c>>st)*half + (c&(half-1)), partner c^half,
// left iff (c & half)==0.  (Same algebra as rounds 1-2, which passed.)
// ---------------------------------------------------------------------------
__global__ __launch_bounds__(256, 4)
void pr_butterfly(const float* __restrict__ x,
                  const float2* __restrict__ cs,
                  const float* __restrict__ diag,
                  float* __restrict__ out) {
    __shared__ __align__(16) float tile[256 * 32];   // 32 KB

    const int tid = threadIdx.x;
    const int blk = blockIdx.x;            // 4096 blocks
    const int b   = blk >> 7;              // 0..31
    const int ptB = (blk & 127) * 32;      // 32-point window

    const int lane = tid & 63;
    const int wv   = tid >> 6;

    const float* __restrict__ xb = x + (size_t)b * 256 * 4096;
    float* __restrict__ ob = out + (size_t)b * 256 * 4096;

    // ---- Phase A: global -> LDS, 8 rows x 128 B per wave per iter ----
    {
        const int r3 = lane >> 3;          // row within group
        const int p8 = lane & 7;           // 16B slot within row
#pragma unroll
        for (int it = 0; it < 8; ++it) {
            const int s   = (it * 4 + wv) & 7;
            const int row = it * 32 + wv * 8 + r3;
            const float* g = xb + (size_t)row * 4096 + (size_t)ptB
                           + (size_t)((p8 ^ s) * 4);
            __builtin_amdgcn_global_load_lds(
                (const __attribute__((address_space(1))) void*)g,
                (__attribute__((address_space(3))) void*)(tile + (it * 32 + wv * 8) * 32),
                16, 0, 0);
        }
    }
    __syncthreads();

    // ---- Phase B: compute ----
    const int A   = lane >> 2;                 // channel block 0..15
    const int ptf = wv * 8 + (lane & 3) * 2;   // this thread's 2 points
    const float2* __restrict__ csb = cs + (size_t)b * 1024;
    const float* __restrict__ dgb  = diag + (size_t)b * 256;

    const int swz0 = ((A * 2) & 7) << 2;
    const int swz1 = ((A * 2 + 1) & 7) << 2;
    const int base = A * 16 * 32;

    float2 y[16];
#pragma unroll
    for (int j = 0; j < 8; ++j)
        y[j] = *(const float2*)&tile[base + j * 32 + (ptf ^ swz0)];
#pragma unroll
    for (int j = 8; j < 16; ++j)
        y[j] = *(const float2*)&tile[base + j * 32 + (ptf ^ swz1)];

    // Stages 1..4 — register-local (8 pairs among the 16 channels).
#pragma unroll
    for (int st = 1; st <= 4; ++st) {
        const int h = 1 << (st - 1);
        const float4* c4 = (const float4*)(csb + ((st - 1) * 128 + A * 8));
        float4 cq[4];
#pragma unroll
        for (int i = 0; i < 4; ++i) cq[i] = c4[i];
#pragma unroll
        for (int q = 0; q < 8; ++q) {
            const int jl = ((q >> (st - 1)) << st) | (q & (h - 1));
            const int jr = jl | h;
            const float cc = (q & 1) ? cq[q >> 1].z : cq[q >> 1].x;
            const float ss = (q & 1) ? cq[q >> 1].w : cq[q >> 1].y;
            const float2 l = y[jl];
            const float2 r = y[jr];
            y[jl].x = fmaf(cc, l.x, ss * r.x);
            y[jl].y = fmaf(cc, l.y, ss * r.y);
            y[jr].x = fmaf(cc, r.x, -(ss * l.x));
            y[jr].y = fmaf(cc, r.y, -(ss * l.y));
        }
    }

    // Stages 5..8 — cross-lane via shfl_xor(4/8/16/32).
#pragma unroll
    for (int st = 5; st <= 8; ++st) {
        const int k  = st - 5;
        const int xm = 4 << k;
        const bool left = ((A >> k) & 1) == 0;
        int p0;
        if (st == 5)      p0 = 512 + (A >> 1) * 16;
        else if (st == 6) p0 = 640 + (A >> 2) * 32 + (A & 1) * 16;
        else if (st == 7) p0 = 768 + (A & 3) * 16;            // (A>>3)*64 + (A&3)*16
        else              p0 = 896 + (A & 7) * 16;
        if (st == 7) p0 += (A >> 3) * 64;
        const float4* c4 = (const float4*)(csb + p0);
        float4 cq[8];
#pragma unroll
        for (int i = 0; i < 8; ++i) cq[i] = c4[i];
#pragma unroll
        for (int j = 0; j < 16; ++j) {
            const float cc = (j & 1) ? cq[j >> 1].z : cq[j >> 1].x;
            const float ss = (j & 1) ? cq[j >> 1].w : cq[j >> 1].y;
            const float se = left ? ss : -ss;
            const float ox = __shfl_xor(y[j].x, xm, 64);
            const float oy = __shfl_xor(y[j].y, xm, 64);
            y[j].x = fmaf(cc, y[j].x, se * ox);
            y[j].y = fmaf(cc, y[j].y, se * oy);
        }
    }

    // Diagonal scale.
    {
        const float4* d4 = (const float4*)(dgb + A * 16);
#pragma unroll
        for (int i = 0; i < 4; ++i) {
            const float4 dv = d4[i];
            y[i * 4 + 0].x *= dv.x;  y[i * 4 + 0].y *= dv.x;
            y[i * 4 + 1].x *= dv.y;  y[i * 4 + 1].y *= dv.y;
            y[i * 4 + 2].x *= dv.z;  y[i * 4 + 2].y *= dv.z;
            y[i * 4 + 3].x *= dv.w;  y[i * 4 + 3].y *= dv.w;
        }
    }

    // Write back to tile (same swizzled slots).
#pragma unroll
    for (int j = 0; j < 8; ++j)
        *(float2*)&tile[base + j * 32 + (ptf ^ swz0)] = y[j];
#pragma unroll
    for (int j = 8; j < 16; ++j)
        *(float2*)&tile[base + j * 32 + (ptf ^ swz1)] = y[j];

    __syncthreads();

    // ---- Phase C: LDS -> global, linear LDS read + swizzled store addr ----
    {
        const int r3 = lane >> 3;
        const int p8 = lane & 7;
#pragma unroll
        for (int it = 0; it < 8; ++it) {
            const int s   = (it * 4 + wv) & 7;
            const int row = it * 32 + wv * 8 + r3;
            const float4 v = *(const float4*)&tile[row * 32 + p8 * 4];
            *(float4*)(ob + (size_t)row * 4096 + (size_t)ptB
                       + (size_t)((p8 ^ s) * 4)) = v;
        }
    }
}

// ---------------------------------------------------------------------------
extern "C" void kernel_launch(void* const* d_in, const int* in_sizes, int n_in,
                              void* d_out, int out_size, void* d_ws, size_t ws_size,
                              hipStream_t stream) {
    const float* x        = (const float*)d_in[0];  // (32,256,64,64)
    const float* mod      = (const float*)d_in[1];  // (32,256)
    const float* angles   = (const float*)d_in[2];  // (1024,)
    const float* diagonal = (const float*)d_in[3];  // (256,)
    const float* w_angle  = (const float*)d_in[4];  // (1024,256)
    const float* w_diag   = (const float*)d_in[5];  // (256,256)
    float* out = (float*)d_out;

    float2* cs   = (float2*)d_ws;                                      // 256 KB
    float*  diag = (float*)((char*)d_ws + 32 * 1024 * sizeof(float2)); // 32 KB

    pr_precompute<<<128, 256, 0, stream>>>(mod, angles, diagonal, w_angle, w_diag, cs, diag);
    pr_butterfly<<<4096, 256, 0, stream>>>(x, cs, diag, out);
}

// Round 4
// 129.740 us; speedup vs baseline: 1.6300x; 1.0080x over previous
//
#include <hip/hip_runtime.h>
#include <math.h>

#define CAPV 0.99f

// ---------------------------------------------------------------------------
// Kernel 1: per-batch angle/diag precompute.
// cs layout (per batch, 1024 float2):
//   region1 [0,512):   stages 1-4, natural pair order p (thread A reads
//                      (st-1)*128 + A*8 + q, q=0..7 -> 4 contiguous float4).
//   region2 [512,1024): stages 5-8 REORDERED by (c0 = c&15, q):
//                      idx = 512 + (st-5)*128 + c0*8 + q, where q enumerates
//                      the thread's 8 left-channels k (bit st-5 of k == 0).
// diag2: transposed: diag2[b*256 + (c&15)*16 + (c>>4)]  -> pass-2 thread c0
//                    reads 16 contiguous floats.
// ---------------------------------------------------------------------------
__global__ void pr_precompute(const float* __restrict__ mod,
                              const float* __restrict__ angles,
                              const float* __restrict__ diagonal,
                              const float* __restrict__ w_angle,
                              const float* __restrict__ w_diag,
                              float2* __restrict__ cs,
                              float* __restrict__ diag2) {
    const int gid = blockIdx.x * blockDim.x + threadIdx.x;   // 0..32767
    const int b = gid >> 10;
    const int p = gid & 1023;

    const float4* m  = (const float4*)(mod + (size_t)b * 256);
    const float4* wr = (const float4*)(w_angle + (size_t)p * 256);
    float acc = 0.f;
#pragma unroll
    for (int k = 0; k < 64; ++k) {
        float4 a = m[k], c = wr[k];
        acc += a.x * c.x + a.y * c.y + a.z * c.z + a.w * c.w;
    }
    const float ang = angles[p] + tanhf(acc);
    float sv, cv;
    sincosf(ang, &sv, &cv);

    int outp;
    if (p < 512) {
        outp = p;
    } else {
        const int st   = (p >> 7) + 1;        // 5..8
        const int lp   = p & 127;
        const int half = 1 << (st - 1);
        const int c    = ((lp >> (st - 1)) << st) | (lp & (half - 1));
        const int k    = c >> 4;              // bit (st-5) of k is 0
        const int c0   = c & 15;
        int q;
        if (st == 5)      q = k >> 1;
        else if (st == 6) q = (k >> 2) * 2 + (k & 1);
        else if (st == 7) q = (k >> 3) * 4 + (k & 3);
        else              q = k;
        outp = 512 + (st - 5) * 128 + c0 * 8 + q;
    }
    cs[(size_t)b * 1024 + outp] = make_float2(cv, sv);

    if (gid < 32 * 256) {
        const int b2 = gid >> 8;
        const int cd = gid & 255;
        const float4* m2 = (const float4*)(mod + (size_t)b2 * 256);
        const float4* w2 = (const float4*)(w_diag + (size_t)cd * 256);
        float a2 = 0.f;
#pragma unroll
        for (int k = 0; k < 64; ++k) {
            float4 u = m2[k], v = w2[k];
            a2 += u.x * v.x + u.y * v.y + u.z * v.z + u.w * v.w;
        }
        float bd = tanhf(diagonal[cd]);
        bd = fminf(fmaxf(bd, -CAPV), CAPV);
        float d = bd + tanhf(a2);
        d = fminf(fmaxf(d, -CAPV), CAPV);
        diag2[(size_t)b2 * 256 + (cd & 15) * 16 + (cd >> 4)] = d;
    }
}

// ---------------------------------------------------------------------------
// Kernel 2: two-pass butterfly, zero shuffles.
// Block = 256 thr, tile = 256 ch x 32 pts (exactly 32 KB -> 5 blocks/CU).
// LDS swizzle (16B-slot granularity): swz(c) = (c ^ (c>>4)) & 7; physical
// slot = logical_slot ^ swz(c). Varies with A (=c>>4) for pass-1 contiguous
// reads AND with c0 (=c&15) for pass-2 strided reads -> <=2-way per
// quarter-wave on every phase (free).
// Phase A: global_load_lds, swizzle folded into global source addr (m173).
// Pass 1: thread = 16 contiguous ch (c=A*16+j) x 2 pts; stages 1-4 local.
// Pass 2: thread = 16 strided ch (c=c0+16k) x 2 pts; stages 5-8 local
//         (q->k maps mirror the precompute reorder), diag applied.
// Phase C: linear LDS b128 reads, inverse-swizzled global float4 stores.
// ---------------------------------------------------------------------------
__global__ __launch_bounds__(256, 5)
void pr_butterfly(const float* __restrict__ x,
                  const float2* __restrict__ cs,
                  const float* __restrict__ diag2,
                  float* __restrict__ out) {
    __shared__ __align__(16) float tile[256 * 32];   // 32 KB exactly

    const int tid = threadIdx.x;
    const int blk = blockIdx.x;            // 4096 blocks
    const int b   = blk >> 7;              // 0..31
    const int ptB = (blk & 127) * 32;      // 32-point window

    const int lane = tid & 63;
    const int wv   = tid >> 6;

    const float* __restrict__ xb = x + (size_t)b * 256 * 4096;
    float* __restrict__ ob = out + (size_t)b * 256 * 4096;

    // ---- Phase A: global -> LDS (linear dest, pre-swizzled source) ----
    {
        const int r3 = lane >> 3;          // row-in-group
        const int p8 = lane & 7;           // physical 16B slot
#pragma unroll
        for (int it = 0; it < 8; ++it) {
            const int row = it * 32 + wv * 8 + r3;
            const int swz = (row ^ (row >> 4)) & 7;
            const float* g = xb + (size_t)row * 4096 + (size_t)ptB
                           + (size_t)((p8 ^ swz) << 2);
            __builtin_amdgcn_global_load_lds(
                (const __attribute__((address_space(1))) void*)g,
                (__attribute__((address_space(3))) void*)(tile + (it * 32 + wv * 8) * 32),
                16, 0, 0);
        }
    }
    __syncthreads();

    const int A  = lane >> 2;                  // 0..15 (pass-1 group / pass-2 c0)
    const int pq = lane & 3;
    const int p  = wv * 8 + pq * 2;            // this thread's 2 points
    const int pl = p & 3;                      // 0 or 2
    const int ps = p >> 2;                     // logical slot
    const float2* __restrict__ csb = cs + (size_t)b * 1024;

    // ---- Pass 1: 16 contiguous channels, stages 1..4 ----
    {
        float2 y[16];
#pragma unroll
        for (int j = 0; j < 16; ++j) {
            const int c   = A * 16 + j;
            const int swz = (j ^ A) & 7;
            y[j] = *(const float2*)&tile[c * 32 + ((ps ^ swz) << 2) + pl];
        }

#pragma unroll
        for (int st = 1; st <= 4; ++st) {
            const int h = 1 << (st - 1);
            const float4* c4 = (const float4*)(csb + ((st - 1) * 128 + A * 8));
            float4 cq[4];
#pragma unroll
            for (int i = 0; i < 4; ++i) cq[i] = c4[i];
#pragma unroll
            for (int q = 0; q < 8; ++q) {
                const int jl = ((q >> (st - 1)) << st) | (q & (h - 1));
                const int jr = jl | h;
                const float cc = (q & 1) ? cq[q >> 1].z : cq[q >> 1].x;
                const float ss = (q & 1) ? cq[q >> 1].w : cq[q >> 1].y;
                const float2 l = y[jl];
                const float2 r = y[jr];
                y[jl].x = fmaf(cc, l.x, ss * r.x);
                y[jl].y = fmaf(cc, l.y, ss * r.y);
                y[jr].x = fmaf(cc, r.x, -(ss * l.x));
                y[jr].y = fmaf(cc, r.y, -(ss * l.y));
            }
        }

#pragma unroll
        for (int j = 0; j < 16; ++j) {
            const int c   = A * 16 + j;
            const int swz = (j ^ A) & 7;
            *(float2*)&tile[c * 32 + ((ps ^ swz) << 2) + pl] = y[j];
        }
    }
    __syncthreads();

    // ---- Pass 2: 16 stride-16 channels (c = A + 16k), stages 5..8 + diag ----
    {
        float2 z[16];
#pragma unroll
        for (int k = 0; k < 16; ++k) {
            const int c   = A + k * 16;
            const int swz = (A ^ k) & 7;
            z[k] = *(const float2*)&tile[c * 32 + ((ps ^ swz) << 2) + pl];
        }

#pragma unroll
        for (int st = 5; st <= 8; ++st) {
            const int sb = st - 5;
            const float4* c4 = (const float4*)csb + 256 + sb * 64 + A * 4;
            float4 cq[4];
#pragma unroll
            for (int i = 0; i < 4; ++i) cq[i] = c4[i];
#pragma unroll
            for (int q = 0; q < 8; ++q) {
                int k;
                if (st == 5)      k = q * 2;
                else if (st == 6) k = (q >> 1) * 4 + (q & 1);
                else if (st == 7) k = (q >> 2) * 8 + (q & 3);
                else              k = q;
                const int k2 = k + (1 << sb);
                const float cc = (q & 1) ? cq[q >> 1].z : cq[q >> 1].x;
                const float ss = (q & 1) ? cq[q >> 1].w : cq[q >> 1].y;
                const float2 l = z[k];
                const float2 r = z[k2];
                z[k].x  = fmaf(cc, l.x, ss * r.x);
                z[k].y  = fmaf(cc, l.y, ss * r.y);
                z[k2].x = fmaf(cc, r.x, -(ss * l.x));
                z[k2].y = fmaf(cc, r.y, -(ss * l.y));
            }
        }

        // Diagonal (transposed layout: 16 contiguous floats per thread).
        {
            const float4* d4 = (const float4*)(diag2 + (size_t)b * 256 + A * 16);
#pragma unroll
            for (int i = 0; i < 4; ++i) {
                const float4 dv = d4[i];
                z[i * 4 + 0].x *= dv.x;  z[i * 4 + 0].y *= dv.x;
                z[i * 4 + 1].x *= dv.y;  z[i * 4 + 1].y *= dv.y;
                z[i * 4 + 2].x *= dv.z;  z[i * 4 + 2].y *= dv.z;
                z[i * 4 + 3].x *= dv.w;  z[i * 4 + 3].y *= dv.w;
            }
        }

#pragma unroll
        for (int k = 0; k < 16; ++k) {
            const int c   = A + k * 16;
            const int swz = (A ^ k) & 7;
            *(float2*)&tile[c * 32 + ((ps ^ swz) << 2) + pl] = z[k];
        }
    }
    __syncthreads();

    // ---- Phase C: LDS -> global (linear LDS read, swizzled store addr) ----
    {
        const int r3 = lane >> 3;
        const int p8 = lane & 7;
#pragma unroll
        for (int it = 0; it < 8; ++it) {
            const int row = it * 32 + wv * 8 + r3;
            const int swz = (row ^ (row >> 4)) & 7;
            const float4 v = *(const float4*)&tile[row * 32 + p8 * 4];
            *(float4*)(ob + (size_t)row * 4096 + (size_t)ptB
                       + (size_t)((p8 ^ swz) << 2)) = v;
        }
    }
}

// ---------------------------------------------------------------------------
extern "C" void kernel_launch(void* const* d_in, const int* in_sizes, int n_in,
                              void* d_out, int out_size, void* d_ws, size_t ws_size,
                              hipStream_t stream) {
    const float* x        = (const float*)d_in[0];  // (32,256,64,64)
    const float* mod      = (const float*)d_in[1];  // (32,256)
    const float* angles   = (const float*)d_in[2];  // (1024,)
    const float* diagonal = (const float*)d_in[3];  // (256,)
    const float* w_angle  = (const float*)d_in[4];  // (1024,256)
    const float* w_diag   = (const float*)d_in[5];  // (256,256)
    float* out = (float*)d_out;

    float2* cs    = (float2*)d_ws;                                      // 256 KB
    float*  diag2 = (float*)((char*)d_ws + 32 * 1024 * sizeof(float2)); // 32 KB

    pr_precompute<<<128, 256, 0, stream>>>(mod, angles, diagonal, w_angle, w_diag, cs, diag2);
    pr_butterfly<<<4096, 256, 0, stream>>>(x, cs, diag2, out);
}

// Round 6
// 90.486 us; speedup vs baseline: 2.3371x; 1.4338x over previous
//
#include <hip/hip_runtime.h>
#include <math.h>

#define CAPV 0.99f

typedef float f32x4 __attribute__((ext_vector_type(4)));

// Raw workgroup barrier that does NOT drain vmcnt (keeps prefetch loads in
// flight across it). lgkmcnt(0) guarantees this wave's LDS writes landed;
// "memory" clobbers stop the compiler moving LDS ops across the barrier.
#define WG_BARRIER() do {                                   \
    asm volatile("s_waitcnt lgkmcnt(0)" ::: "memory");      \
    __builtin_amdgcn_s_barrier();                           \
    asm volatile("" ::: "memory");                          \
} while (0)

// ---------------------------------------------------------------------------
// Kernel 1: per-batch angle/diag precompute, 4 lanes per output + shfl reduce.
// cs layout per batch (1024 float2):
//   [0,512):    stages 1-4, natural pair order.
//   [512,1024): stages 5-8 reordered by (c0=c&15, q) (pass-2 friendly).
// diag2 transposed: diag2[b*256 + (c&15)*16 + (c>>4)].
// ---------------------------------------------------------------------------
__global__ void pr_precompute(const float* __restrict__ mod,
                              const float* __restrict__ angles,
                              const float* __restrict__ diagonal,
                              const float* __restrict__ w_angle,
                              const float* __restrict__ w_diag,
                              float2* __restrict__ cs,
                              float* __restrict__ diag2) {
    const int gid = blockIdx.x * blockDim.x + threadIdx.x;  // 0..163839
    const int o = gid >> 2;                                  // output id
    const int r = gid & 3;                                   // reduce lane

    if (o < 32768) {                       // ---- cos/sin outputs ----
        const int b = o >> 10;
        const int p = o & 1023;
        const float4* m = (const float4*)(mod + (size_t)b * 256);
        const float4* w = (const float4*)(w_angle + (size_t)p * 256);
        float acc = 0.f;
#pragma unroll
        for (int i = 0; i < 16; ++i) {
            const float4 a = m[i * 4 + r];
            const float4 c = w[i * 4 + r];
            acc += a.x * c.x + a.y * c.y + a.z * c.z + a.w * c.w;
        }
        acc += __shfl_xor(acc, 1, 64);
        acc += __shfl_xor(acc, 2, 64);
        if (r == 0) {
            const float ang = angles[p] + tanhf(acc);
            float sv, cv;
            sincosf(ang, &sv, &cv);
            int outp;
            if (p < 512) {
                outp = p;
            } else {
                const int st   = (p >> 7) + 1;        // 5..8
                const int lp   = p & 127;
                const int half = 1 << (st - 1);
                const int c    = ((lp >> (st - 1)) << st) | (lp & (half - 1));
                const int k    = c >> 4;
                const int c0   = c & 15;
                int q;
                if (st == 5)      q = k >> 1;
                else if (st == 6) q = (k >> 2) * 2 + (k & 1);
                else if (st == 7) q = (k >> 3) * 4 + (k & 3);
                else              q = k;
                outp = 512 + (st - 5) * 128 + c0 * 8 + q;
            }
            cs[(size_t)b * 1024 + outp] = make_float2(cv, sv);
        }
    } else {                               // ---- diag outputs ----
        const int o2 = o - 32768;          // 0..8191
        const int b2 = o2 >> 8;
        const int cd = o2 & 255;
        const float4* m = (const float4*)(mod + (size_t)b2 * 256);
        const float4* w = (const float4*)(w_diag + (size_t)cd * 256);
        float acc = 0.f;
#pragma unroll
        for (int i = 0; i < 16; ++i) {
            const float4 a = m[i * 4 + r];
            const float4 c = w[i * 4 + r];
            acc += a.x * c.x + a.y * c.y + a.z * c.z + a.w * c.w;
        }
        acc += __shfl_xor(acc, 1, 64);
        acc += __shfl_xor(acc, 2, 64);
        if (r == 0) {
            float bd = tanhf(diagonal[cd]);
            bd = fminf(fmaxf(bd, -CAPV), CAPV);
            float d = bd + tanhf(acc);
            d = fminf(fmaxf(d, -CAPV), CAPV);
            diag2[(size_t)b2 * 256 + (cd & 15) * 16 + (cd >> 4)] = d;
        }
    }
}

// ---------------------------------------------------------------------------
// Kernel 2: pipelined two-pass butterfly.
// Block = 256 thr, 4 tiles of (256 ch x 32 pts), single 32 KB LDS buffer,
// cross-tile prefetch into registers (global->reg early, reg->LDS late).
// Grid 1024 = 4 blocks/CU, 16 waves/CU, all co-resident.
//
// LDS swizzle (16B slots): s(c) = (((c ^ (c>>4)) & 3) << 1. Bank bits[2:1]
// carry A&3 (the quarter-wave-varying dim in both passes), bit0 carries the
// point-slot bit -> every quarter-wave LDS access hits 32 distinct banks.
//
// Sync per tile (2 raw barriers, no vmcnt drain):
//   ds_write own rows -> BAR -> pass1 (intra-wave) -> lgkm fence ->
//   pass2+diag -> BAR -> phase C (own rows, nt stores).
// Cross-wave hazards only at the two barriers: phaseC(t-1) reads and
// ds_write(t) touch the same per-wave-owned rows (no cross-wave overlap).
// ---------------------------------------------------------------------------
__global__ __launch_bounds__(256, 4)
void pr_butterfly(const float* __restrict__ x,
                  const float2* __restrict__ cs,
                  const float* __restrict__ diag2,
                  float* __restrict__ out) {
    __shared__ __align__(16) float tile[256 * 32];   // 32 KB

    const int tid  = threadIdx.x;
    const int blk  = blockIdx.x;          // 1024 blocks
    const int b    = blk >> 5;            // 0..31
    const int wcol = blk & 31;            // 4-window group

    const int lane = tid & 63;
    const int wv   = tid >> 6;
    const int r3   = lane >> 3;           // staging row-in-group
    const int p8   = lane & 7;            // staging 16B slot
    const int A    = lane >> 2;           // channel group 0..15
    const int pq   = lane & 3;
    const int p    = wv * 8 + pq * 2;     // this thread's 2 points
    const int pl   = p & 3;
    const int ps   = p >> 2;              // logical 16B slot of the points

    const float* __restrict__ xb = x + (size_t)b * 1048576;
    float* __restrict__ ob = out + (size_t)b * 1048576;
    const float2* __restrict__ csb = cs + (size_t)b * 1024;

    // Prologue: prefetch tile 0 into registers (linear global reads).
    float4 rf[8];
    {
        const int ptB = wcol * 128;
#pragma unroll
        for (int it = 0; it < 8; ++it) {
            const int row = it * 32 + wv * 8 + r3;
            rf[it] = *(const float4*)(xb + (size_t)row * 4096 + ptB + p8 * 4);
        }
    }

    for (int t = 0; t < 4; ++t) {
        const int ptB = wcol * 128 + t * 32;

        // (a) regs -> LDS, own rows, swizzled slots.
#pragma unroll
        for (int it = 0; it < 8; ++it) {
            const int row = it * 32 + wv * 8 + r3;
            const int swz = ((row ^ (row >> 4)) & 3) << 1;
            *(float4*)&tile[row * 32 + ((p8 ^ swz) << 2)] = rf[it];
        }

        // (b) issue prefetch of tile t+1 (stays in flight across barriers).
        if (t < 3) {
#pragma unroll
            for (int it = 0; it < 8; ++it) {
                const int row = it * 32 + wv * 8 + r3;
                rf[it] = *(const float4*)(xb + (size_t)row * 4096 + (ptB + 32) + p8 * 4);
            }
        }

        // (c) all waves' rows staged.
        WG_BARRIER();

        // ---- pass 1: 16 contiguous channels (c = A*16+j), stages 1..4 ----
        {
            float2 y[16];
#pragma unroll
            for (int j = 0; j < 16; ++j) {
                const int swz = ((j ^ A) & 3) << 1;
                y[j] = *(const float2*)&tile[(A * 16 + j) * 32 + ((ps ^ swz) << 2) + pl];
            }

#pragma unroll
            for (int st = 1; st <= 4; ++st) {
                const int h = 1 << (st - 1);
                const float4* c4 = (const float4*)(csb + ((st - 1) * 128 + A * 8));
                float4 cq[4];
#pragma unroll
                for (int i = 0; i < 4; ++i) cq[i] = c4[i];
#pragma unroll
                for (int q = 0; q < 8; ++q) {
                    const int jl = ((q >> (st - 1)) << st) | (q & (h - 1));
                    const int jr = jl | h;
                    const float cc = (q & 1) ? cq[q >> 1].z : cq[q >> 1].x;
                    const float ss = (q & 1) ? cq[q >> 1].w : cq[q >> 1].y;
                    const float2 l = y[jl];
                    const float2 r = y[jr];
                    y[jl].x = fmaf(cc, l.x, ss * r.x);
                    y[jl].y = fmaf(cc, l.y, ss * r.y);
                    y[jr].x = fmaf(cc, r.x, -(ss * l.x));
                    y[jr].y = fmaf(cc, r.y, -(ss * l.y));
                }
            }

#pragma unroll
            for (int j = 0; j < 16; ++j) {
                const int swz = ((j ^ A) & 3) << 1;
                *(float2*)&tile[(A * 16 + j) * 32 + ((ps ^ swz) << 2) + pl] = y[j];
            }
        }

        // (e) pass1 -> pass2 exchange is intra-wave only: LDS fence, no barrier.
        asm volatile("s_waitcnt lgkmcnt(0)" ::: "memory");

        // ---- pass 2: 16 stride-16 channels (c = A + 16k), stages 5..8 ----
        {
            float2 z[16];
#pragma unroll
            for (int k = 0; k < 16; ++k) {
                const int swz = ((A ^ k) & 3) << 1;
                z[k] = *(const float2*)&tile[(A + k * 16) * 32 + ((ps ^ swz) << 2) + pl];
            }

#pragma unroll
            for (int st = 5; st <= 8; ++st) {
                const int sb = st - 5;
                const float4* c4 = (const float4*)csb + 256 + sb * 64 + A * 4;
                float4 cq[4];
#pragma unroll
                for (int i = 0; i < 4; ++i) cq[i] = c4[i];
#pragma unroll
                for (int q = 0; q < 8; ++q) {
                    int k;
                    if (st == 5)      k = q * 2;
                    else if (st == 6) k = (q >> 1) * 4 + (q & 1);
                    else if (st == 7) k = (q >> 2) * 8 + (q & 3);
                    else              k = q;
                    const int k2 = k + (1 << sb);
                    const float cc = (q & 1) ? cq[q >> 1].z : cq[q >> 1].x;
                    const float ss = (q & 1) ? cq[q >> 1].w : cq[q >> 1].y;
                    const float2 l = z[k];
                    const float2 r = z[k2];
                    z[k].x  = fmaf(cc, l.x, ss * r.x);
                    z[k].y  = fmaf(cc, l.y, ss * r.y);
                    z[k2].x = fmaf(cc, r.x, -(ss * l.x));
                    z[k2].y = fmaf(cc, r.y, -(ss * l.y));
                }
            }

            // Diagonal (transposed: 16 contiguous floats for this thread).
            {
                const float4* d4 = (const float4*)(diag2 + (size_t)b * 256 + A * 16);
#pragma unroll
                for (int i = 0; i < 4; ++i) {
                    const float4 dv = d4[i];
                    z[i * 4 + 0].x *= dv.x;  z[i * 4 + 0].y *= dv.x;
                    z[i * 4 + 1].x *= dv.y;  z[i * 4 + 1].y *= dv.y;
                    z[i * 4 + 2].x *= dv.z;  z[i * 4 + 2].y *= dv.z;
                    z[i * 4 + 3].x *= dv.w;  z[i * 4 + 3].y *= dv.w;
                }
            }

#pragma unroll
            for (int k = 0; k < 16; ++k) {
                const int swz = ((A ^ k) & 3) << 1;
                *(float2*)&tile[(A + k * 16) * 32 + ((ps ^ swz) << 2) + pl] = z[k];
            }
        }

        // (g) all waves' pass-2 writes visible.
        WG_BARRIER();

        // (h) phase C: swizzled LDS read of own rows, linear nontemporal store.
#pragma unroll
        for (int it = 0; it < 8; ++it) {
            const int row = it * 32 + wv * 8 + r3;
            const int swz = ((row ^ (row >> 4)) & 3) << 1;
            const float4 v = *(const float4*)&tile[row * 32 + ((p8 ^ swz) << 2)];
            f32x4 nv;
            nv.x = v.x; nv.y = v.y; nv.z = v.z; nv.w = v.w;
            __builtin_nontemporal_store(nv,
                (f32x4*)(ob + (size_t)row * 4096 + ptB + p8 * 4));
        }
        // Next iteration's (a) overwrites only this wave's own rows: the only
        // hazard is with our own (h) reads above -> same-wave DS order + the
        // WG_BARRIER at (c) / compiler LDS alias conservatism cover it.
    }
}

// ---------------------------------------------------------------------------
extern "C" void kernel_launch(void* const* d_in, const int* in_sizes, int n_in,
                              void* d_out, int out_size, void* d_ws, size_t ws_size,
                              hipStream_t stream) {
    const float* x        = (const float*)d_in[0];  // (32,256,64,64)
    const float* mod      = (const float*)d_in[1];  // (32,256)
    const float* angles   = (const float*)d_in[2];  // (1024,)
    const float* diagonal = (const float*)d_in[3];  // (256,)
    const float* w_angle  = (const float*)d_in[4];  // (1024,256)
    const float* w_diag   = (const float*)d_in[5];  // (256,256)
    float* out = (float*)d_out;

    float2* cs    = (float2*)d_ws;                                      // 256 KB
    float*  diag2 = (float*)((char*)d_ws + 32 * 1024 * sizeof(float2)); // 32 KB

    pr_precompute<<<640, 256, 0, stream>>>(mod, angles, diagonal, w_angle, w_diag, cs, diag2);
    pr_butterfly<<<1024, 256, 0, stream>>>(x, cs, diag2, out);
}